// Round 2
// baseline (805.551 us; speedup 1.0000x reference)
//
#include <hip/hip_runtime.h>
#include <math.h>

// B=512, T=256, F=D=1024 fp32.
// Algebra: q = z@Wq^T+bq ; qk = q@Wk (bk drops: softmax-invariant);
// scores[b,t] = past[b,t,:].qk[b,:] ; ctx[b] = softmax-weighted sum of past rows;
// out = ctx@Wv^T + bv (Wv applied AFTER attention since sum(w)=1).

#define MM 512
#define NN 1024
#define KK 1024
#define KZ 8            // split-K factor for GEMMs
#define KS (KK / KZ)    // 128 K per split
#define BM 128
#define BN 128
#define BK 16
#define LDW (BM + 4)    // 132 floats: pad keeps 16B align, kills scatter conflicts

// ---------------- fp32 GEMM: 128x128 tile, 8x8 micro, dbuf LDS, split-K=8 ----
// BT=1: Bm is [N,K] (torch Linear W). NSUM: # of A split-K partials summed on load.
// BIAS added at kz==0 partial only.
template<int BT, int NSUM, int BIAS>
__global__ __launch_bounds__(256) void gemm_f32(const float* __restrict__ A,
        const float* __restrict__ Bm, const float* __restrict__ bias,
        float* __restrict__ C)
{
    __shared__ float As[2][BK][LDW];
    __shared__ float Bs[2][BK][LDW];
    const int tid = threadIdx.x;
    const int tn = tid & 15, tm = tid >> 4;
    const int n0 = blockIdx.x * BN, m0 = blockIdx.y * BM, kz = blockIdx.z;
    const int kbeg = kz * KS;
    const int ar = tid >> 1;          // 0..127: row for A (and B when BT=1)
    const int aq = (tid & 1) * 2;     // float4 pair: k-cols (aq+j)*4

    float4 va[2], vb[2];

    auto loadA = [&](int kt, float4* v) {
        #pragma unroll
        for (int j = 0; j < 2; ++j) {
            const float* ap = A + (size_t)(m0 + ar) * KK + kbeg + kt * BK + (aq + j) * 4;
            float4 x = *(const float4*)ap;
            #pragma unroll
            for (int p = 1; p < NSUM; ++p) {
                float4 w = *(const float4*)(ap + (size_t)p * MM * NN);
                x.x += w.x; x.y += w.y; x.z += w.z; x.w += w.w;
            }
            v[j] = x;
        }
    };
    auto loadB = [&](int kt, float4* v) {
        if (BT) {
            #pragma unroll
            for (int j = 0; j < 2; ++j)
                v[j] = *(const float4*)(Bm + (size_t)(n0 + ar) * KK + kbeg + kt * BK + (aq + j) * 4);
        } else {
            #pragma unroll
            for (int j = 0; j < 2; ++j) {
                const int idx = tid * 2 + j;            // 0..511
                const int krow = idx >> 5, nq = idx & 31;
                v[j] = *(const float4*)(Bm + (size_t)(kbeg + kt * BK + krow) * NN + n0 + nq * 4);
            }
        }
    };
    auto storeLDS = [&](int buf, const float4* a, const float4* b) {
        #pragma unroll
        for (int j = 0; j < 2; ++j) {   // A: transpose scatter (2-way alias = free)
            const int kk = (aq + j) * 4;
            As[buf][kk+0][ar] = a[j].x; As[buf][kk+1][ar] = a[j].y;
            As[buf][kk+2][ar] = a[j].z; As[buf][kk+3][ar] = a[j].w;
        }
        if (BT) {
            #pragma unroll
            for (int j = 0; j < 2; ++j) {
                const int kk = (aq + j) * 4;
                Bs[buf][kk+0][ar] = b[j].x; Bs[buf][kk+1][ar] = b[j].y;
                Bs[buf][kk+2][ar] = b[j].z; Bs[buf][kk+3][ar] = b[j].w;
            }
        } else {
            #pragma unroll
            for (int j = 0; j < 2; ++j) {
                const int idx = tid * 2 + j;
                const int krow = idx >> 5, nq = idx & 31;
                *(float4*)&Bs[buf][krow][nq * 4] = b[j];
            }
        }
    };

    float c[8][8] = {};

    loadA(0, va); loadB(0, vb);
    storeLDS(0, va, vb);
    __syncthreads();

    #pragma unroll 1
    for (int kt = 0; kt < KS / BK; ++kt) {     // 8 iterations
        const int cur = kt & 1;
        const bool more = (kt + 1 < KS / BK);
        if (more) { loadA(kt + 1, va); loadB(kt + 1, vb); }  // prefetch under compute
        #pragma unroll
        for (int k = 0; k < BK; ++k) {
            float a[8], b[8];
            *(float4*)&a[0] = *(const float4*)&As[cur][k][tm * 8];
            *(float4*)&a[4] = *(const float4*)&As[cur][k][tm * 8 + 4];
            *(float4*)&b[0] = *(const float4*)&Bs[cur][k][tn * 8];
            *(float4*)&b[4] = *(const float4*)&Bs[cur][k][tn * 8 + 4];
            #pragma unroll
            for (int i = 0; i < 8; ++i)
                #pragma unroll
                for (int j = 0; j < 8; ++j)
                    c[i][j] = fmaf(a[i], b[j], c[i][j]);
        }
        if (more) {
            storeLDS(cur ^ 1, va, vb);   // other buffer: single barrier per iter
            __syncthreads();
        }
    }

    float* Cp = C + (size_t)kz * MM * NN;
    #pragma unroll
    for (int i = 0; i < 8; ++i) {
        const int m = m0 + tm * 8 + i;
        float* cp = Cp + (size_t)m * NN + n0 + tn * 8;
        float4 o0 = make_float4(c[i][0], c[i][1], c[i][2], c[i][3]);
        float4 o1 = make_float4(c[i][4], c[i][5], c[i][6], c[i][7]);
        if (BIAS && kz == 0) {
            const float* bp = bias + n0 + tn * 8;
            o0.x += bp[0]; o0.y += bp[1]; o0.z += bp[2]; o0.w += bp[3];
            o1.x += bp[4]; o1.y += bp[5]; o1.z += bp[6]; o1.w += bp[7];
        }
        *(float4*)cp = o0;
        *(float4*)(cp + 4) = o1;
    }
}

// ---------------- streaming attention, split-T=2: 1024 blocks ----------------
// Block (b,p) handles t in [p*128, p*128+128) with its own online softmax;
// writes unnormalized acc + (m,l) for exact merge.
__global__ __launch_bounds__(256) void attn_stream(const float* __restrict__ past,
        const float* __restrict__ qk8, float* __restrict__ macc, float* __restrict__ ml)
{
    const int b = blockIdx.x >> 1, p = blockIdx.x & 1;
    const int e = threadIdx.x;
    const int lane = e & 63, w = e >> 6;
    __shared__ float red[2][4][8];

    const float* qp = qk8 + (size_t)b * NN + e * 4;
    float4 q4 = *(const float4*)qp;
    #pragma unroll
    for (int pp = 1; pp < KZ; ++pp) {     // sum split-K partials of qk
        float4 t = *(const float4*)(qp + (size_t)pp * MM * NN);
        q4.x += t.x; q4.y += t.y; q4.z += t.z; q4.w += t.w;
    }

    float4 acc = make_float4(0.f, 0.f, 0.f, 0.f);
    float m = -INFINITY, l = 0.f;
    const float* base = past + (size_t)b * 256 * 1024 + (size_t)p * 128 * 1024 + e * 4;

    for (int t0 = 0; t0 < 128; t0 += 8) {
        const int buf = (t0 >> 3) & 1;
        float4 r[8];
        float s[8];
        #pragma unroll
        for (int j = 0; j < 8; ++j)
            r[j] = *(const float4*)(base + (size_t)(t0 + j) * 1024);
        #pragma unroll
        for (int j = 0; j < 8; ++j)
            s[j] = q4.x*r[j].x + q4.y*r[j].y + q4.z*r[j].z + q4.w*r[j].w;
        #pragma unroll
        for (int j = 0; j < 8; ++j) {
            #pragma unroll
            for (int off = 1; off < 64; off <<= 1)
                s[j] += __shfl_xor(s[j], off, 64);
        }
        if (lane == 0) {
            #pragma unroll
            for (int j = 0; j < 8; ++j) red[buf][w][j] = s[j];
        }
        __syncthreads();
        #pragma unroll
        for (int j = 0; j < 8; ++j)
            s[j] = red[buf][0][j] + red[buf][1][j] + red[buf][2][j] + red[buf][3][j];

        float cmax = s[0];
        #pragma unroll
        for (int j = 1; j < 8; ++j) cmax = fmaxf(cmax, s[j]);
        const float mn = fmaxf(m, cmax);
        const float alpha = __expf(m - mn);      // first iter: exp(-inf)=0
        float pe[8], sum = 0.f;
        #pragma unroll
        for (int j = 0; j < 8; ++j) { pe[j] = __expf(s[j] - mn); sum += pe[j]; }
        l = l * alpha + sum;
        acc.x *= alpha; acc.y *= alpha; acc.z *= alpha; acc.w *= alpha;
        #pragma unroll
        for (int j = 0; j < 8; ++j) {
            acc.x = fmaf(pe[j], r[j].x, acc.x);
            acc.y = fmaf(pe[j], r[j].y, acc.y);
            acc.z = fmaf(pe[j], r[j].z, acc.z);
            acc.w = fmaf(pe[j], r[j].w, acc.w);
        }
        m = mn;
    }
    *(float4*)(macc + ((size_t)p * MM + b) * NN + e * 4) = acc;
    if (e == 0) {
        ml[((size_t)p * MM + b) * 2]     = m;
        ml[((size_t)p * MM + b) * 2 + 1] = l;
    }
}

// ---------------- exact merge of the two split-T partials --------------------
__global__ __launch_bounds__(256) void attn_merge(const float* __restrict__ macc,
        const float* __restrict__ ml, float* __restrict__ ctx)
{
    const int b = blockIdx.x, e = threadIdx.x;
    const float m0 = ml[(size_t)b * 2],        l0 = ml[(size_t)b * 2 + 1];
    const float m1 = ml[(MM + (size_t)b) * 2], l1 = ml[(MM + (size_t)b) * 2 + 1];
    const float M = fmaxf(m0, m1);
    const float w0 = __expf(m0 - M), w1 = __expf(m1 - M);
    const float inv = 1.0f / (w0 * l0 + w1 * l1);
    float4 a0 = *(const float4*)(macc + (size_t)b * NN + e * 4);
    float4 a1 = *(const float4*)(macc + ((size_t)MM + b) * NN + e * 4);
    float4 o = make_float4((w0*a0.x + w1*a1.x) * inv, (w0*a0.y + w1*a1.y) * inv,
                           (w0*a0.z + w1*a1.z) * inv, (w0*a0.w + w1*a1.w) * inv);
    *(float4*)(ctx + (size_t)b * NN + e * 4) = o;
}

// ---------------- final: out = sum_kz o8[kz] + bv ----------------------------
__global__ __launch_bounds__(256) void final_out(const float* __restrict__ o8,
        const float* __restrict__ bv, float* __restrict__ out)
{
    const size_t i = ((size_t)blockIdx.x * 256 + threadIdx.x) * 4;
    float4 a = *(const float4*)(o8 + i);
    #pragma unroll
    for (int p = 1; p < KZ; ++p) {
        float4 t = *(const float4*)(o8 + (size_t)p * MM * NN + i);
        a.x += t.x; a.y += t.y; a.z += t.z; a.w += t.w;
    }
    const int n = (int)(i & 1023);
    float4 bb = *(const float4*)(bv + n);
    a.x += bb.x; a.y += bb.y; a.z += bb.z; a.w += bb.w;
    *(float4*)(out + i) = a;
}

extern "C" void kernel_launch(void* const* d_in, const int* in_sizes, int n_in,
                              void* d_out, int out_size, void* d_ws, size_t ws_size,
                              hipStream_t stream) {
    const float* z    = (const float*)d_in[0];
    const float* past = (const float*)d_in[1];
    const float* Wq   = (const float*)d_in[2];
    const float* Wk   = (const float*)d_in[3];
    const float* Wv   = (const float*)d_in[4];
    const float* bq   = (const float*)d_in[5];
    // d_in[6] = bk: softmax-invariant, unused.
    const float* bv   = (const float*)d_in[7];
    float* out = (float*)d_out;

    // ws layout (floats): q8[8*512*1024] | qk8[8*512*1024] | macc[2*512*1024] | ml[2048] | ctx[512*1024]
    float* q8   = (float*)d_ws;
    float* qk8  = q8 + (size_t)KZ * MM * NN;
    float* macc = qk8 + (size_t)KZ * MM * NN;
    float* ml   = macc + (size_t)2 * MM * NN;
    float* ctx  = ml + 2048;
    float* o8   = q8;   // q partials dead after GEMM2 -> reuse for out partials

    dim3 g(NN / BN, MM / BM, KZ), blk(256);
    gemm_f32<1, 1, 1><<<g, blk, 0, stream>>>(z,   Wq, bq,      q8);   // q  = z @ Wq^T + bq
    gemm_f32<0, KZ, 0><<<g, blk, 0, stream>>>(q8, Wk, nullptr, qk8);  // qk = q @ Wk
    attn_stream<<<dim3(2 * MM), blk, 0, stream>>>(past, qk8, macc, ml);
    attn_merge<<<dim3(MM), blk, 0, stream>>>(macc, ml, ctx);
    gemm_f32<1, 1, 0><<<g, blk, 0, stream>>>(ctx, Wv, nullptr, o8);   // ctx @ Wv^T
    final_out<<<dim3(MM), blk, 0, stream>>>(o8, bv, out);             // + bv
}